// Round 4
// baseline (341.296 us; speedup 1.0000x reference)
//
#include <hip/hip_runtime.h>
#include <math.h>

#define BB 2
#define TT 2048
#define DD 2048
#define HH 16
#define KVHN 4
#define HDIM 128
#define NKV 3072   // packed q|k|v row width

typedef unsigned short u16;
typedef unsigned int u32;
typedef __bf16 bf16x8 __attribute__((ext_vector_type(8)));
typedef float  f32x4  __attribute__((ext_vector_type(4)));

#define AS1 __attribute__((address_space(1)))
#define AS3 __attribute__((address_space(3)))

__device__ __forceinline__ void dma16(const u16* g, u16* l) {
  __builtin_amdgcn_global_load_lds((const AS1 u32*)g, (AS3 u32*)l, 16, 0, 0);
}

__device__ __forceinline__ u16 f2bf(float f) {
  u32 u = __float_as_uint(f);
  u32 r = (u + 0x7FFFu + ((u >> 16) & 1u)) >> 16;
  return (u16)r;
}
__device__ __forceinline__ float bf2f(u32 h) { return __uint_as_float(h << 16); }

__device__ __forceinline__ u32 pack2(float a, float b) {
  union { __bf16 h[2]; u32 u; } cv;
  cv.h[0] = (__bf16)a; cv.h[1] = (__bf16)b;
  return cv.u;
}

// ---------------- cast fp32 -> bf16 ----------------------------------------
__global__ __launch_bounds__(256) void castf2b(const float* __restrict__ in,
                                               u16* __restrict__ out) {
  size_t i4 = (size_t)blockIdx.x * 256 + threadIdx.x;
  float4 v = *(const float4*)(in + i4 * 4);
  ushort4 o;
  o.x = f2bf(v.x); o.y = f2bf(v.y); o.z = f2bf(v.z); o.w = f2bf(v.w);
  *(ushort4*)(out + i4 * 4) = o;
}

// ---------------- transpose + cast: W[K][N] fp32 -> WT[N][K] bf16 ----------
__global__ __launch_bounds__(256) void tcast(const float* __restrict__ W,
                                             u16* __restrict__ WT,
                                             int K, int N) {
  __shared__ float tile[32][33];
  const int n0 = blockIdx.x * 32, k0 = blockIdx.y * 32;
  const int r = threadIdx.x >> 3;
  const int c4 = (threadIdx.x & 7) * 4;
  float4 v = *(const float4*)(W + (size_t)(k0 + r) * N + n0 + c4);
  tile[r][c4 + 0] = v.x; tile[r][c4 + 1] = v.y;
  tile[r][c4 + 2] = v.z; tile[r][c4 + 3] = v.w;
  __syncthreads();
  ushort4 o;
  o.x = f2bf(tile[c4 + 0][r]); o.y = f2bf(tile[c4 + 1][r]);
  o.z = f2bf(tile[c4 + 2][r]); o.w = f2bf(tile[c4 + 3][r]);
  *(ushort4*)(WT + (size_t)(n0 + r) * K + k0 + c4) = o;
}

// ---------------- counted-vmcnt MFMA GEMM, BK=32 tri-buffer ----------------
// C = A @ BT^T.  BM=128, BN=256, BK=32, 512 thr = 8 waves (2M x 4N).
// Tri-buffered LDS (3 x 24KB = 72KB -> 2 blocks/CU, 4 waves/SIMD).
// Raw s_barrier + counted s_waitcnt vmcnt(N): prefetch DMAs (distance 2)
// stay in flight across barriers.  64B LDS rows, 4-chunk XOR swizzle applied
// on the pre-swizzled GLOBAL source (linear LDS dest) and on ds_read chunk.
template <int OUT_BF16>
__global__ __launch_bounds__(512) void gemm8p(const u16* __restrict__ A,
                                              const u16* __restrict__ BT,
                                              void* __restrict__ Cv,
                                              int N, int K) {
  __shared__ u16 lds[3 * 12288];   // per buffer: A 128x32 (4096) | B 256x32 (8192)
  const int t = threadIdx.x;
  const int l = t & 63, w = t >> 6;
  const int lm = l & 15, quad = l >> 4;
  const int wm = w & 1, wn = w >> 1;
  const int m0 = blockIdx.y * 128, n0 = blockIdx.x * 256;
  const int wu = __builtin_amdgcn_readfirstlane(w);

  // staging source pointers (pre-swizzled global col) + uniform LDS dests
  const u16* srcA; int dstA;
  const u16* srcB[2]; int dstB[2];
  {
    int p0 = wu * 64, p = p0 + l;
    int row = p >> 2, c = (p & 3) ^ (row & 3);
    srcA = A + (size_t)(m0 + row) * K + c * 8;
    dstA = p0 * 8;
  }
  #pragma unroll
  for (int i = 0; i < 2; ++i) {
    int p0 = (wu * 2 + i) * 64, p = p0 + l;
    int row = p >> 2, c = (p & 3) ^ (row & 3);
    srcB[i] = BT + (size_t)(n0 + row) * K + c * 8;
    dstB[i] = 4096 + p0 * 8;
  }

  f32x4 acc[4][4];
  #pragma unroll
  for (int i = 0; i < 4; ++i)
    #pragma unroll
    for (int j = 0; j < 4; ++j) acc[i][j] = (f32x4){0.f, 0.f, 0.f, 0.f};

  auto stage = [&](int bsel) {
    u16* buf = &lds[bsel * 12288];
    dma16(srcA, buf + dstA); srcA += 32;
    #pragma unroll
    for (int i = 0; i < 2; ++i) { dma16(srcB[i], buf + dstB[i]); srcB[i] += 32; }
  };

  stage(0); stage(1); stage(2);           // 9 loads/wave in flight (3 K-tiles)

  const int NT = K >> 5;
  int bsel = 0;
  const int xc = lm & 3;
  for (int tI = 0; tI < NT; ++tI) {
    // tile tI's 3 loads are the oldest outstanding; allow 2 newer tiles in flight
    if (tI + 2 < NT)      asm volatile("s_waitcnt vmcnt(6)" ::: "memory");
    else if (tI + 1 < NT) asm volatile("s_waitcnt vmcnt(3)" ::: "memory");
    else                  asm volatile("s_waitcnt vmcnt(0)" ::: "memory");
    asm volatile("s_barrier" ::: "memory");   // raw: no vmcnt(0) drain

    const u16* Ab = &lds[bsel * 12288];
    const u16* Bb = Ab + 4096;
    const int ch = (quad ^ xc) * 8;
    bf16x8 a[4], b[4];
    #pragma unroll
    for (int i = 0; i < 4; ++i)
      a[i] = *(const bf16x8*)&Ab[(wm * 64 + i * 16 + lm) * 32 + ch];
    #pragma unroll
    for (int j = 0; j < 4; ++j)
      b[j] = *(const bf16x8*)&Bb[(wn * 64 + j * 16 + lm) * 32 + ch];
    __builtin_amdgcn_s_setprio(1);
    #pragma unroll
    for (int i = 0; i < 4; ++i)
      #pragma unroll
      for (int j = 0; j < 4; ++j)
        acc[i][j] = __builtin_amdgcn_mfma_f32_16x16x32_bf16(a[i], b[j], acc[i][j], 0, 0, 0);
    __builtin_amdgcn_s_setprio(0);
    asm volatile("s_barrier" ::: "memory");   // all waves done reading buf bsel
    if (tI + 3 < NT) stage(bsel);             // overwrite just-freed buffer
    bsel = (bsel == 2) ? 0 : bsel + 1;
  }

  #pragma unroll
  for (int i = 0; i < 4; ++i) {
    #pragma unroll
    for (int r = 0; r < 4; ++r) {
      size_t gr = (size_t)(m0 + wm * 64 + i * 16 + quad * 4 + r);
      #pragma unroll
      for (int j = 0; j < 4; ++j) {
        int gc = n0 + wn * 64 + j * 16 + lm;
        if (OUT_BF16) ((u16*)Cv)[gr * N + gc] = f2bf(acc[i][j][r]);
        else          ((float*)Cv)[gr * N + gc] = acc[i][j][r];
      }
    }
  }
}

// ---------------- RoPE in-place on packed QKV rows (q scaled) --------------
__global__ __launch_bounds__(256) void rope2(u16* p) {
  const int row = blockIdx.x;
  const int pos = row & (TT - 1);
  u16* base = p + (size_t)row * NKV;
  float e0[5], e1[5];
  #pragma unroll
  for (int i = 0; i < 5; ++i) {
    int item = threadIdx.x + i * 256;
    int h20 = item >> 6, f = item & 63;
    int col = (h20 < 16) ? h20 * 128 : 2048 + (h20 - 16) * 128;
    u32 u = *(const u32*)(base + col + 2 * f);
    e0[i] = bf2f(u & 0xffffu);
    e1[i] = bf2f(u >> 16);
  }
  __syncthreads();
  #pragma unroll
  for (int i = 0; i < 5; ++i) {
    int item = threadIdx.x + i * 256;
    int h20 = item >> 6, f = item & 63;
    int col = (h20 < 16) ? h20 * 128 : 2048 + (h20 - 16) * 128;
    float sc = (h20 < 16) ? 0.08838834764831845f : 1.0f;
    float inv = exp2f((float)f * -0.20762050593046898f);  // 10000^(-f/64)
    float ang = (float)pos * inv;
    float sn, cs;
    sincosf(ang, &sn, &cs);
    base[col + f]      = f2bf((e0[i] * cs - e1[i] * sn) * sc);
    base[col + 64 + f] = f2bf((e0[i] * sn + e1[i] * cs) * sc);
  }
}

// ---------------- V transpose: QKV v-part -> Vt[(b*4+vh)*128+d][T] ---------
__global__ __launch_bounds__(256) void vtrans(const u16* __restrict__ QKV,
                                              u16* __restrict__ Vt) {
  __shared__ u16 tl[64][72];
  const int t0 = blockIdx.x * 64;
  const int y  = blockIdx.y;        // 0..7
  const int b  = blockIdx.z;
  #pragma unroll
  for (int i = 0; i < 2; ++i) {
    int idx = threadIdx.x + i * 256;
    int r = idx >> 3, c = (idx & 7) * 8;
    *(uint4*)&tl[r][c] =
        *(const uint4*)(QKV + (size_t)(b * TT + t0 + r) * NKV + 2560 + y * 64 + c);
  }
  __syncthreads();
  const int vh = y >> 1;
  #pragma unroll
  for (int i = 0; i < 2; ++i) {
    int idx = threadIdx.x + i * 256;
    int dr = idx >> 3, tc = (idx & 7) * 8;
    u16 tmp[8];
    #pragma unroll
    for (int j = 0; j < 8; ++j) tmp[j] = tl[tc + j][dr];
    int dloc = (y & 1) * 64 + dr;
    *(uint4*)(Vt + (size_t)((b * KVHN + vh) * HDIM + dloc) * TT + t0 + tc) =
        *(const uint4*)tmp;
  }
}

// ---------------- MFMA flash attention v5: counted-vmcnt tri-buffer --------
// KVBLK=32.  LDS: 3x(K 8KB + V 8KB) + P 4KB = 52KB -> 3 blocks/CU.
// Prefetch distance 2; per body: own-wave s_waitcnt vmcnt(N) THEN raw
// s_barrier (no vmcnt(0) drain in the loop).  Stage tile t+3 after the
// second barrier into the buffer freed by tile t.
__global__ __launch_bounds__(256, 3) void attn5(const u16* __restrict__ QKV,
                                                const u16* __restrict__ Vt,
                                                u16* __restrict__ Ob) {
  __shared__ u16 Ks[3 * 4096];     // [32][128] per buffer, 16-chunk XOR rows
  __shared__ u16 Vs[3 * 4096];     // [64][64] per buffer, 8-chunk XOR rows
  __shared__ u16 Pw[4 * 512];
  const int t = threadIdx.x;
  const int l = t & 63, w = t >> 6;
  const int lm = l & 15, quad = l >> 4;
  const int h = blockIdx.y, b = blockIdx.z;
  const int qbase = (blockIdx.x + (blockIdx.y & 7)) & 31;
  const int qt = (blockIdx.y & 8) ? (31 - qbase) : qbase;
  const int kvh = h >> 2;
  const int q0 = qt * 64;
  const int last = 2 * qt + 1;
  const int wu = __builtin_amdgcn_readfirstlane(w);
  u16* pwv = &Pw[w * 512];
  constexpr float L2E = 1.4426950408889634f;

  bf16x8 qf[4];
  {
    size_t r0 = (size_t)(b * TT + q0 + w * 16 + lm) * NKV + h * HDIM;
    #pragma unroll
    for (int ks = 0; ks < 4; ++ks)
      qf[ks] = *(const bf16x8*)(QKV + r0 + ks * 32 + quad * 8);
  }

  f32x4 o[8];
  #pragma unroll
  for (int i = 0; i < 8; ++i) o[i] = (f32x4){0.f, 0.f, 0.f, 0.f};
  float m_ = -1e30f, l_ = 0.f;

  // per-thread staging pointers (advance by one 32-row KV tile per stage)
  const u16 *kg[2], *vg[2];
  int koff[2], voff[2];
  #pragma unroll
  for (int i = 0; i < 2; ++i) {
    int p0 = (wu * 2 + i) * 64, p = p0 + l;
    int krow = p >> 4, kcp = p & 15, kcl = kcp ^ (krow & 15);
    kg[i] = QKV + (size_t)(b * TT + krow) * NKV + 2048 + kvh * HDIM + kcl * 8;
    koff[i] = p0 * 8;
    int vrow = p >> 3, vphys = p & 7, vcl = vphys ^ (vrow & 7);
    int vd = vrow + (vcl >> 2) * 64, vtch = vcl & 3;
    vg[i] = Vt + (size_t)((b * KVHN + kvh) * HDIM + vd) * TT + vtch * 8;
    voff[i] = p0 * 8;
  }

  auto stageKV = [&](int bsel) {   // 4 dma16 per wave
    u16* kd = Ks + bsel * 4096;
    u16* vd = Vs + bsel * 4096;
    #pragma unroll
    for (int i = 0; i < 2; ++i) {
      dma16(kg[i], kd + koff[i]);  kg[i] += 32 * NKV;
      dma16(vg[i], vd + voff[i]);  vg[i] += 32;
    }
  };

  // prologue: stage tiles 0..min(2,last)
  stageKV(0);
  if (1 <= last) stageKV(1);
  if (2 <= last) stageKV(2);

  const int qrow = q0 + w * 16 + lm;

  int bs = 0;
  for (int kt = 0; kt <= last; ++kt) {
    // own-wave wait for tile kt's 4 DMAs, keeping newer tiles in flight
    if (kt + 2 <= last)      asm volatile("s_waitcnt vmcnt(8)" ::: "memory");
    else if (kt + 1 <= last) asm volatile("s_waitcnt vmcnt(4)" ::: "memory");
    else                     asm volatile("s_waitcnt vmcnt(0)" ::: "memory");
    asm volatile("s_barrier" ::: "memory");   // raw: no drain

    const u16* kcur = Ks + bs * 4096;
    const u16* vcur = Vs + bs * 4096;

    // S^T = K . Q^T
    f32x4 s[2];
    s[0] = (f32x4){0.f, 0.f, 0.f, 0.f};
    s[1] = (f32x4){0.f, 0.f, 0.f, 0.f};
    __builtin_amdgcn_s_setprio(1);
    #pragma unroll
    for (int ks = 0; ks < 4; ++ks) {
      #pragma unroll
      for (int mt = 0; mt < 2; ++mt) {
        bf16x8 kb = *(const bf16x8*)&kcur[(mt * 16 + lm) * 128 + (((ks * 4 + quad) ^ lm) * 8)];
        s[mt] = __builtin_amdgcn_mfma_f32_16x16x32_bf16(kb, qf[ks], s[mt], 0, 0, 0);
      }
    }
    __builtin_amdgcn_s_setprio(0);

    // causal mask on diagonal tiles
    if (kt >= 2 * qt) {
      #pragma unroll
      for (int mt = 0; mt < 2; ++mt)
        #pragma unroll
        for (int r = 0; r < 4; ++r) {
          int kv = kt * 32 + mt * 16 + quad * 4 + r;
          if (kv > qrow) s[mt][r] = -1e30f;
        }
    }

    // online softmax with defer-max (THR=8)
    float mx = -1e30f;
    #pragma unroll
    for (int mt = 0; mt < 2; ++mt)
      #pragma unroll
      for (int r = 0; r < 4; ++r) mx = fmaxf(mx, s[mt][r]);
    mx = fmaxf(mx, __shfl_xor(mx, 16));
    mx = fmaxf(mx, __shfl_xor(mx, 32));
    bool upd = mx > m_ + 8.f;
    float mn = upd ? mx : m_;
    float al = upd ? exp2f((m_ - mn) * L2E) : 1.f;
    m_ = mn;
    float sum = 0.f;
    #pragma unroll
    for (int mt = 0; mt < 2; ++mt)
      #pragma unroll
      for (int r = 0; r < 4; ++r) {
        float pv = exp2f((s[mt][r] - mn) * L2E);
        s[mt][r] = pv;
        sum += pv;
      }
    sum += __shfl_xor(sum, 16);
    sum += __shfl_xor(sum, 32);
    l_ = l_ * al + sum;

    // P -> LDS (per-wave region, 128B rows, 8-slot XOR)
    #pragma unroll
    for (int mt = 0; mt < 2; ++mt) {
      u32 p01 = pack2(s[mt][0], s[mt][1]);
      u32 p23 = pack2(s[mt][2], s[mt][3]);
      int c = mt * 2 + (quad >> 1);
      int addr = (lm >> 1) * 64 + ((lm & 1) * 4 + (c ^ ((lm >> 1) & 3))) * 8 + (quad & 1) * 4;
      uint2 uv; uv.x = p01; uv.y = p23;
      *(uint2*)&pwv[addr] = uv;
    }
    if (__any(upd)) {
      #pragma unroll
      for (int i = 0; i < 8; ++i)
        #pragma unroll
        for (int r = 0; r < 4; ++r) o[i][r] *= al;
    }

    // O^T += V^T . P^T
    int paddr = (lm >> 1) * 64 + ((lm & 1) * 4 + (quad ^ ((lm >> 1) & 3))) * 8;
    bf16x8 pb = *(const bf16x8*)&pwv[paddr];
    __builtin_amdgcn_s_setprio(1);
    #pragma unroll
    for (int mt2 = 0; mt2 < 8; ++mt2) {
      int vrow = (mt2 & 3) * 16 + lm;
      int vphys = ((mt2 >> 2) * 4 + quad) ^ (vrow & 7);
      bf16x8 vb = *(const bf16x8*)&vcur[vrow * 64 + vphys * 8];
      o[mt2] = __builtin_amdgcn_mfma_f32_16x16x32_bf16(vb, pb, o[mt2], 0, 0, 0);
    }
    __builtin_amdgcn_s_setprio(0);

    asm volatile("s_barrier" ::: "memory");   // all waves done with buffer bs
    if (kt + 3 <= last) stageKV(bs);          // refill freed buffer with tile kt+3
    bs = (bs == 2) ? 0 : bs + 1;
  }

  // epilogue: O^T -> LDS transpose (reuse dead K buffers) -> coalesced stores
  __syncthreads();
  u16* esc = Ks + (w >> 1) * 4096 + (w & 1) * 2048;
  float inv = 1.f / l_;
  #pragma unroll
  for (int mt2 = 0; mt2 < 8; ++mt2) {
    u32 a0 = pack2(o[mt2][0] * inv, o[mt2][1] * inv);
    u32 a1 = pack2(o[mt2][2] * inv, o[mt2][3] * inv);
    int phys = (mt2 * 2 + (quad >> 1)) ^ (lm & 7);
    int addr = lm * 128 + phys * 8 + (quad & 1) * 4;
    uint2 uv; uv.x = a0; uv.y = a1;
    *(uint2*)&esc[addr] = uv;
  }
  #pragma unroll
  for (int i = 0; i < 4; ++i) {
    int p = i * 64 + l;
    int row = p >> 4, cl = p & 15;
    int cph = cl ^ (row & 7);
    uint4 val = *(const uint4*)&esc[row * 128 + cph * 8];
    *(uint4*)(Ob + (size_t)(b * TT + q0 + w * 16 + row) * DD + h * HDIM + cl * 8) = val;
  }
}

extern "C" void kernel_launch(void* const* d_in, const int* in_sizes, int n_in,
                              void* d_out, int out_size, void* d_ws, size_t ws_size,
                              hipStream_t stream) {
  const float* x  = (const float*)d_in[0];
  const float* Wq = (const float*)d_in[1];
  const float* Wk = (const float*)d_in[2];
  const float* Wv = (const float*)d_in[3];
  const float* Wo = (const float*)d_in[4];
  float* out = (float*)d_out;

  // ws (u16 elems): xb @0 (8M, -> Ob) | WqkvT @8M (6M, -> Vt) | WoT @14.68M (4M)
  u16* xb    = (u16*)d_ws;
  u16* WqkvT = xb + 8388608;
  u16* WoT   = xb + 14680064;
  u16* Vt    = WqkvT;               // alias, live after QKV GEMM
  u16* Ob    = xb;                  // alias, live after QKV GEMM
  u16* QKVb  = (u16*)d_out;         // bf16 [4096][3072] in the 32MB out buffer

  dim3 blk(256);
  castf2b<<<8192, blk, 0, stream>>>(x, xb);
  tcast<<<dim3(64, 64), blk, 0, stream>>>(Wq, WqkvT, DD, DD);
  tcast<<<dim3(16, 64), blk, 0, stream>>>(Wk, WqkvT + (size_t)2048 * DD, DD, 512);
  tcast<<<dim3(16, 64), blk, 0, stream>>>(Wv, WqkvT + (size_t)2560 * DD, DD, 512);
  tcast<<<dim3(64, 64), blk, 0, stream>>>(Wo, WoT, DD, DD);

  gemm8p<1><<<dim3(NKV / 256, 32), dim3(512), 0, stream>>>(xb, WqkvT, QKVb, NKV, DD);
  rope2<<<BB * TT, blk, 0, stream>>>(QKVb);
  vtrans<<<dim3(32, 8, BB), blk, 0, stream>>>(QKVb, Vt);
  attn5<<<dim3(32, HH, BB), blk, 0, stream>>>(QKVb, Vt, Ob);
  gemm8p<0><<<dim3(DD / 256, 32), dim3(512), 0, stream>>>(Ob, WoT, out, DD, DD);
}

// Round 5
// 337.839 us; speedup vs baseline: 1.0102x; 1.0102x over previous
//
#include <hip/hip_runtime.h>
#include <math.h>

#define BB 2
#define TT 2048
#define DD 2048
#define HH 16
#define KVHN 4
#define HDIM 128
#define NKV 3072   // packed q|k|v row width

typedef unsigned short u16;
typedef unsigned int u32;
typedef __bf16 bf16x8 __attribute__((ext_vector_type(8)));
typedef float  f32x4  __attribute__((ext_vector_type(4)));

#define AS1 __attribute__((address_space(1)))
#define AS3 __attribute__((address_space(3)))

__device__ __forceinline__ void dma16(const u16* g, u16* l) {
  __builtin_amdgcn_global_load_lds((const AS1 u32*)g, (AS3 u32*)l, 16, 0, 0);
}

__device__ __forceinline__ u16 f2bf(float f) {
  u32 u = __float_as_uint(f);
  u32 r = (u + 0x7FFFu + ((u >> 16) & 1u)) >> 16;
  return (u16)r;
}
__device__ __forceinline__ float bf2f(u32 h) { return __uint_as_float(h << 16); }

__device__ __forceinline__ u32 pack2(float a, float b) {
  union { __bf16 h[2]; u32 u; } cv;
  cv.h[0] = (__bf16)a; cv.h[1] = (__bf16)b;
  return cv.u;
}

// ---------------- cast fp32 -> bf16 ----------------------------------------
__global__ __launch_bounds__(256) void castf2b(const float* __restrict__ in,
                                               u16* __restrict__ out) {
  size_t i4 = (size_t)blockIdx.x * 256 + threadIdx.x;
  float4 v = *(const float4*)(in + i4 * 4);
  ushort4 o;
  o.x = f2bf(v.x); o.y = f2bf(v.y); o.z = f2bf(v.z); o.w = f2bf(v.w);
  *(ushort4*)(out + i4 * 4) = o;
}

// ---------------- transpose + cast: W[K][N] fp32 -> WT[N][K] bf16 ----------
__global__ __launch_bounds__(256) void tcast(const float* __restrict__ W,
                                             u16* __restrict__ WT,
                                             int K, int N) {
  __shared__ float tile[32][33];
  const int n0 = blockIdx.x * 32, k0 = blockIdx.y * 32;
  const int r = threadIdx.x >> 3;
  const int c4 = (threadIdx.x & 7) * 4;
  float4 v = *(const float4*)(W + (size_t)(k0 + r) * N + n0 + c4);
  tile[r][c4 + 0] = v.x; tile[r][c4 + 1] = v.y;
  tile[r][c4 + 2] = v.z; tile[r][c4 + 3] = v.w;
  __syncthreads();
  ushort4 o;
  o.x = f2bf(tile[c4 + 0][r]); o.y = f2bf(tile[c4 + 1][r]);
  o.z = f2bf(tile[c4 + 2][r]); o.w = f2bf(tile[c4 + 3][r]);
  *(ushort4*)(WT + (size_t)(n0 + r) * K + k0 + c4) = o;
}

// ---------------- phase-interleaved counted-vmcnt MFMA GEMM ----------------
// C = A @ BT^T.  BM=128, BN=256, BK=64, 512 thr = 8 waves (2M x 4N).
// Tri-buffered LDS (3 x 48KB = 144KB, 1 block/CU, 8 waves).  Per K-tile:
//   s_waitcnt vmcnt(6); s_barrier            (tile t landed for ALL waves;
//                                             tile t+1's 6 loads stay in flight)
//   phase ks=0: 8 ds_read | 3 dma(t+2) | bar | 16 MFMA (setprio) | bar
//   phase ks=1: 8 ds_read | 3 dma(t+2) | bar | 16 MFMA (setprio) | bar
// vmcnt never drains to 0 mid-loop (T3+T4).  LDS rows 128B, 8-chunk XOR
// applied on pre-swizzled GLOBAL source + ds_read chunk (both-sides rule);
// fragment mapping identical to the proven R3 BK=64 kernel.
template <int OUT_BF16>
__global__ __launch_bounds__(512) void gemm4p(const u16* __restrict__ A,
                                              const u16* __restrict__ BT,
                                              void* __restrict__ Cv,
                                              int N, int K) {
  __shared__ u16 lds[3 * 24576];   // per buffer: A[128][64] (8192) | B[256][64] (16384)
  const int t = threadIdx.x;
  const int l = t & 63, w = t >> 6;
  const int lm = l & 15, quad = l >> 4;
  const int wm = w & 1, wn = w >> 1;
  const int m0 = blockIdx.y * 128, n0 = blockIdx.x * 256;
  const int wu = __builtin_amdgcn_readfirstlane(w);
  const int tid = wu * 64 + l;

  // staging: A 2 chunks/thread, B 4 chunks/thread; pre-swizzled global col
  const u16* srcA[2]; int dstA[2];
  const u16* srcB[4]; int dstB[4];
  #pragma unroll
  for (int i = 0; i < 2; ++i) {
    int p = tid + i * 512;
    int row = p >> 3, c = (p & 7) ^ (row & 7);
    srcA[i] = A + (size_t)(m0 + row) * K + c * 8;
    dstA[i] = p * 8;
  }
  #pragma unroll
  for (int i = 0; i < 4; ++i) {
    int p = tid + i * 512;
    int row = p >> 3, c = (p & 7) ^ (row & 7);
    srcB[i] = BT + (size_t)(n0 + row) * K + c * 8;
    dstB[i] = 8192 + p * 8;
  }

  f32x4 acc[4][4];
  #pragma unroll
  for (int i = 0; i < 4; ++i)
    #pragma unroll
    for (int j = 0; j < 4; ++j) acc[i][j] = (f32x4){0.f, 0.f, 0.f, 0.f};

  auto stage_full = [&](int bsel) {   // 6 dma16/thread (whole K-tile)
    u16* buf = &lds[bsel * 24576];
    #pragma unroll
    for (int i = 0; i < 2; ++i) { dma16(srcA[i], buf + dstA[i]); srcA[i] += 64; }
    #pragma unroll
    for (int i = 0; i < 4; ++i) { dma16(srcB[i], buf + dstB[i]); srcB[i] += 64; }
  };

  stage_full(0); stage_full(1);       // tiles 0,1 in flight (12 loads/thread)

  const int NT = K >> 6;
  for (int tI = 0; tI < NT; ++tI) {
    // tile tI's 6 loads are oldest; allow tile tI+1's 6 to stay in flight
    if (tI + 1 < NT) asm volatile("s_waitcnt vmcnt(6)" ::: "memory");
    else             asm volatile("s_waitcnt vmcnt(0)" ::: "memory");
    asm volatile("s_barrier" ::: "memory");

    const u16* Ab = &lds[(tI % 3) * 24576];
    const u16* Bb = Ab + 8192;
    u16* nbuf = &lds[((tI + 2) % 3) * 24576];
    const bool st = (tI + 2) < NT;

    #pragma unroll
    for (int ks = 0; ks < 2; ++ks) {
      bf16x8 a[4], b[4];
      #pragma unroll
      for (int i = 0; i < 4; ++i) {
        int row = wm * 64 + i * 16 + lm;
        a[i] = *(const bf16x8*)&Ab[row * 64 + (((ks * 4 + quad) ^ (row & 7)) * 8)];
      }
      #pragma unroll
      for (int j = 0; j < 4; ++j) {
        int row = wn * 64 + j * 16 + lm;
        b[j] = *(const bf16x8*)&Bb[row * 64 + (((ks * 4 + quad) ^ (row & 7)) * 8)];
      }
      if (st) {
        if (ks == 0) {
          dma16(srcA[0], nbuf + dstA[0]); srcA[0] += 64;
          dma16(srcA[1], nbuf + dstA[1]); srcA[1] += 64;
          dma16(srcB[0], nbuf + dstB[0]); srcB[0] += 64;
        } else {
          dma16(srcB[1], nbuf + dstB[1]); srcB[1] += 64;
          dma16(srcB[2], nbuf + dstB[2]); srcB[2] += 64;
          dma16(srcB[3], nbuf + dstB[3]); srcB[3] += 64;
        }
      }
      asm volatile("s_barrier" ::: "memory");   // align waves: reads+stage done
      __builtin_amdgcn_s_setprio(1);
      #pragma unroll
      for (int i = 0; i < 4; ++i)
        #pragma unroll
        for (int j = 0; j < 4; ++j)
          acc[i][j] = __builtin_amdgcn_mfma_f32_16x16x32_bf16(a[i], b[j], acc[i][j], 0, 0, 0);
      __builtin_amdgcn_s_setprio(0);
      asm volatile("s_barrier" ::: "memory");   // MFMA cluster boundary
    }
  }

  #pragma unroll
  for (int i = 0; i < 4; ++i) {
    #pragma unroll
    for (int r = 0; r < 4; ++r) {
      size_t gr = (size_t)(m0 + wm * 64 + i * 16 + quad * 4 + r);
      #pragma unroll
      for (int j = 0; j < 4; ++j) {
        int gc = n0 + wn * 64 + j * 16 + lm;
        if (OUT_BF16) ((u16*)Cv)[gr * N + gc] = f2bf(acc[i][j][r]);
        else          ((float*)Cv)[gr * N + gc] = acc[i][j][r];
      }
    }
  }
}

// ---------------- RoPE in-place on packed QKV rows (q scaled) --------------
__global__ __launch_bounds__(256) void rope2(u16* p) {
  const int row = blockIdx.x;
  const int pos = row & (TT - 1);
  u16* base = p + (size_t)row * NKV;
  float e0[5], e1[5];
  #pragma unroll
  for (int i = 0; i < 5; ++i) {
    int item = threadIdx.x + i * 256;
    int h20 = item >> 6, f = item & 63;
    int col = (h20 < 16) ? h20 * 128 : 2048 + (h20 - 16) * 128;
    u32 u = *(const u32*)(base + col + 2 * f);
    e0[i] = bf2f(u & 0xffffu);
    e1[i] = bf2f(u >> 16);
  }
  __syncthreads();
  #pragma unroll
  for (int i = 0; i < 5; ++i) {
    int item = threadIdx.x + i * 256;
    int h20 = item >> 6, f = item & 63;
    int col = (h20 < 16) ? h20 * 128 : 2048 + (h20 - 16) * 128;
    float sc = (h20 < 16) ? 0.08838834764831845f : 1.0f;
    float inv = exp2f((float)f * -0.20762050593046898f);  // 10000^(-f/64)
    float ang = (float)pos * inv;
    float sn, cs;
    sincosf(ang, &sn, &cs);
    base[col + f]      = f2bf((e0[i] * cs - e1[i] * sn) * sc);
    base[col + 64 + f] = f2bf((e0[i] * sn + e1[i] * cs) * sc);
  }
}

// ---------------- V transpose: QKV v-part -> Vt[(b*4+vh)*128+d][T] ---------
__global__ __launch_bounds__(256) void vtrans(const u16* __restrict__ QKV,
                                              u16* __restrict__ Vt) {
  __shared__ u16 tl[64][72];
  const int t0 = blockIdx.x * 64;
  const int y  = blockIdx.y;        // 0..7
  const int b  = blockIdx.z;
  #pragma unroll
  for (int i = 0; i < 2; ++i) {
    int idx = threadIdx.x + i * 256;
    int r = idx >> 3, c = (idx & 7) * 8;
    *(uint4*)&tl[r][c] =
        *(const uint4*)(QKV + (size_t)(b * TT + t0 + r) * NKV + 2560 + y * 64 + c);
  }
  __syncthreads();
  const int vh = y >> 1;
  #pragma unroll
  for (int i = 0; i < 2; ++i) {
    int idx = threadIdx.x + i * 256;
    int dr = idx >> 3, tc = (idx & 7) * 8;
    u16 tmp[8];
    #pragma unroll
    for (int j = 0; j < 8; ++j) tmp[j] = tl[tc + j][dr];
    int dloc = (y & 1) * 64 + dr;
    *(uint4*)(Vt + (size_t)((b * KVHN + vh) * HDIM + dloc) * TT + t0 + tc) =
        *(const uint4*)tmp;
  }
}

// ---------------- MFMA flash attention v4 (R2/R3 version, 93us proven) -----
__global__ __launch_bounds__(256, 4) void attn4(const u16* __restrict__ QKV,
                                                const u16* __restrict__ Vt,
                                                u16* __restrict__ Ob) {
  __shared__ u16 KsA[32 * 128], KsB[32 * 128];
  __shared__ u16 VsA[64 * 64], VsB[64 * 64];
  __shared__ u16 Pw[4 * 512];
  const int t = threadIdx.x;
  const int l = t & 63, w = t >> 6;
  const int lm = l & 15, quad = l >> 4;
  const int h = blockIdx.y, b = blockIdx.z;
  const int qbase = (blockIdx.x + (blockIdx.y & 7)) & 31;
  const int qt = (blockIdx.y & 8) ? (31 - qbase) : qbase;
  const int kvh = h >> 2;
  const int q0 = qt * 64;
  const int last = 2 * qt + 1;
  const int wu = __builtin_amdgcn_readfirstlane(w);
  u16* pwv = &Pw[w * 512];
  constexpr float L2E = 1.4426950408889634f;

  bf16x8 qf[4];
  {
    size_t r0 = (size_t)(b * TT + q0 + w * 16 + lm) * NKV + h * HDIM;
    #pragma unroll
    for (int ks = 0; ks < 4; ++ks)
      qf[ks] = *(const bf16x8*)(QKV + r0 + ks * 32 + quad * 8);
  }

  f32x4 o[8];
  #pragma unroll
  for (int i = 0; i < 8; ++i) o[i] = (f32x4){0.f, 0.f, 0.f, 0.f};
  float m_ = -1e30f, l_ = 0.f;

  const u16 *kg[2], *vg[2];
  int koff[2], voff[2];
  #pragma unroll
  for (int i = 0; i < 2; ++i) {
    int p0 = (wu * 2 + i) * 64, p = p0 + l;
    int krow = p >> 4, kcp = p & 15, kcl = kcp ^ (krow & 15);
    kg[i] = QKV + (size_t)(b * TT + krow) * NKV + 2048 + kvh * HDIM + kcl * 8;
    koff[i] = p0 * 8;
    int vrow = p >> 3, vphys = p & 7, vcl = vphys ^ (vrow & 7);
    int vd = vrow + (vcl >> 2) * 64, vtch = vcl & 3;
    vg[i] = Vt + (size_t)((b * KVHN + kvh) * HDIM + vd) * TT + vtch * 8;
    voff[i] = p0 * 8;
  }

  #pragma unroll
  for (int i = 0; i < 2; ++i) {
    dma16(kg[i], KsA + koff[i]);
    dma16(vg[i], VsA + voff[i]);
    kg[i] += 32 * NKV;
    vg[i] += 32;
  }

  const int qrow = q0 + w * 16 + lm;

  auto body = [&](int kt, const u16* kcur, const u16* vcur, u16* knx, u16* vnx) {
    __syncthreads();
    const bool pf = kt < last;
    if (pf) {
      #pragma unroll
      for (int i = 0; i < 2; ++i) dma16(vg[i], vnx + voff[i]);
    }

    f32x4 s[2];
    s[0] = (f32x4){0.f, 0.f, 0.f, 0.f};
    s[1] = (f32x4){0.f, 0.f, 0.f, 0.f};
    __builtin_amdgcn_s_setprio(1);
    #pragma unroll
    for (int ks = 0; ks < 4; ++ks) {
      #pragma unroll
      for (int mt = 0; mt < 2; ++mt) {
        bf16x8 kb = *(const bf16x8*)&kcur[(mt * 16 + lm) * 128 + (((ks * 4 + quad) ^ lm) * 8)];
        s[mt] = __builtin_amdgcn_mfma_f32_16x16x32_bf16(kb, qf[ks], s[mt], 0, 0, 0);
      }
    }
    __builtin_amdgcn_s_setprio(0);
    if (pf) {
      #pragma unroll
      for (int i = 0; i < 2; ++i) {
        dma16(kg[i], knx + koff[i]);
        kg[i] += 32 * NKV;
        vg[i] += 32;
      }
    }

    if (kt >= 2 * qt) {
      #pragma unroll
      for (int mt = 0; mt < 2; ++mt)
        #pragma unroll
        for (int r = 0; r < 4; ++r) {
          int kv = kt * 32 + mt * 16 + quad * 4 + r;
          if (kv > qrow) s[mt][r] = -1e30f;
        }
    }

    float mx = -1e30f;
    #pragma unroll
    for (int mt = 0; mt < 2; ++mt)
      #pragma unroll
      for (int r = 0; r < 4; ++r) mx = fmaxf(mx, s[mt][r]);
    mx = fmaxf(mx, __shfl_xor(mx, 16));
    mx = fmaxf(mx, __shfl_xor(mx, 32));
    bool upd = mx > m_ + 8.f;
    float mn = upd ? mx : m_;
    float al = upd ? exp2f((m_ - mn) * L2E) : 1.f;
    m_ = mn;
    float sum = 0.f;
    #pragma unroll
    for (int mt = 0; mt < 2; ++mt)
      #pragma unroll
      for (int r = 0; r < 4; ++r) {
        float pv = exp2f((s[mt][r] - mn) * L2E);
        s[mt][r] = pv;
        sum += pv;
      }
    sum += __shfl_xor(sum, 16);
    sum += __shfl_xor(sum, 32);
    l_ = l_ * al + sum;

    #pragma unroll
    for (int mt = 0; mt < 2; ++mt) {
      u32 p01 = pack2(s[mt][0], s[mt][1]);
      u32 p23 = pack2(s[mt][2], s[mt][3]);
      int c = mt * 2 + (quad >> 1);
      int addr = (lm >> 1) * 64 + ((lm & 1) * 4 + (c ^ ((lm >> 1) & 3))) * 8 + (quad & 1) * 4;
      uint2 uv; uv.x = p01; uv.y = p23;
      *(uint2*)&pwv[addr] = uv;
    }
    if (__any(upd)) {
      #pragma unroll
      for (int i = 0; i < 8; ++i)
        #pragma unroll
        for (int r = 0; r < 4; ++r) o[i][r] *= al;
    }

    int paddr = (lm >> 1) * 64 + ((lm & 1) * 4 + (quad ^ ((lm >> 1) & 3))) * 8;
    bf16x8 pb = *(const bf16x8*)&pwv[paddr];
    __builtin_amdgcn_s_setprio(1);
    #pragma unroll
    for (int mt2 = 0; mt2 < 8; ++mt2) {
      int vrow = (mt2 & 3) * 16 + lm;
      int vphys = ((mt2 >> 2) * 4 + quad) ^ (vrow & 7);
      bf16x8 vb = *(const bf16x8*)&vcur[vrow * 64 + vphys * 8];
      o[mt2] = __builtin_amdgcn_mfma_f32_16x16x32_bf16(vb, pb, o[mt2], 0, 0, 0);
    }
    __builtin_amdgcn_s_setprio(0);
  };

  for (int kt = 0; kt <= last; ++kt) {
    if ((kt & 1) == 0) body(kt, KsA, VsA, KsB, VsB);
    else               body(kt, KsB, VsB, KsA, VsA);
  }

  __syncthreads();
  u16* esc = ((w & 2) ? KsB : KsA) + (w & 1) * 2048;
  float inv = 1.f / l_;
  #pragma unroll
  for (int mt2 = 0; mt2 < 8; ++mt2) {
    u32 a0 = pack2(o[mt2][0] * inv, o[mt2][1] * inv);
    u32 a1 = pack2(o[mt2][2] * inv, o[mt2][3] * inv);
    int phys = (mt2 * 2 + (quad >> 1)) ^ (lm & 7);
    int addr = lm * 128 + phys * 8 + (quad & 1) * 4;
    uint2 uv; uv.x = a0; uv.y = a1;
    *(uint2*)&esc[addr] = uv;
  }
  #pragma unroll
  for (int i = 0; i < 4; ++i) {
    int p = i * 64 + l;
    int row = p >> 4, cl = p & 15;
    int cph = cl ^ (row & 7);
    uint4 val = *(const uint4*)&esc[row * 128 + cph * 8];
    *(uint4*)(Ob + (size_t)(b * TT + q0 + w * 16 + row) * DD + h * HDIM + cl * 8) = val;
  }
}

extern "C" void kernel_launch(void* const* d_in, const int* in_sizes, int n_in,
                              void* d_out, int out_size, void* d_ws, size_t ws_size,
                              hipStream_t stream) {
  const float* x  = (const float*)d_in[0];
  const float* Wq = (const float*)d_in[1];
  const float* Wk = (const float*)d_in[2];
  const float* Wv = (const float*)d_in[3];
  const float* Wo = (const float*)d_in[4];
  float* out = (float*)d_out;

  // ws (u16 elems): xb @0 (8M, -> Ob) | WqkvT @8M (6M, -> Vt) | WoT @14.68M (4M)
  u16* xb    = (u16*)d_ws;
  u16* WqkvT = xb + 8388608;
  u16* WoT   = xb + 14680064;
  u16* Vt    = WqkvT;               // alias, live after QKV GEMM
  u16* Ob    = xb;                  // alias, live after QKV GEMM
  u16* QKVb  = (u16*)d_out;         // bf16 [4096][3072] in the 32MB out buffer

  dim3 blk(256);
  castf2b<<<8192, blk, 0, stream>>>(x, xb);
  tcast<<<dim3(64, 64), blk, 0, stream>>>(Wq, WqkvT, DD, DD);
  tcast<<<dim3(16, 64), blk, 0, stream>>>(Wk, WqkvT + (size_t)2048 * DD, DD, 512);
  tcast<<<dim3(16, 64), blk, 0, stream>>>(Wv, WqkvT + (size_t)2560 * DD, DD, 512);
  tcast<<<dim3(64, 64), blk, 0, stream>>>(Wo, WoT, DD, DD);

  gemm4p<1><<<dim3(NKV / 256, 32), dim3(512), 0, stream>>>(xb, WqkvT, QKVb, NKV, DD);
  rope2<<<BB * TT, blk, 0, stream>>>(QKVb);
  vtrans<<<dim3(32, 8, BB), blk, 0, stream>>>(QKVb, Vt);
  attn4<<<dim3(32, HH, BB), blk, 0, stream>>>(QKVb, Vt, Ob);
  gemm4p<0><<<dim3(DD / 256, 32), dim3(512), 0, stream>>>(Ob, WoT, out, DD, DD);
}

// Round 6
// 325.064 us; speedup vs baseline: 1.0499x; 1.0393x over previous
//
#include <hip/hip_runtime.h>
#include <math.h>

#define BB 2
#define TT 2048
#define DD 2048
#define HH 16
#define KVHN 4
#define HDIM 128
#define NKV 3072   // packed q|k|v row width

typedef unsigned short u16;
typedef unsigned int u32;
typedef __bf16 bf16x8 __attribute__((ext_vector_type(8)));
typedef float  f32x4  __attribute__((ext_vector_type(4)));

#define AS1 __attribute__((address_space(1)))
#define AS3 __attribute__((address_space(3)))

__device__ __forceinline__ void dma16(const u16* g, u16* l) {
  __builtin_amdgcn_global_load_lds((const AS1 u32*)g, (AS3 u32*)l, 16, 0, 0);
}

__device__ __forceinline__ u16 f2bf(float f) {
  u32 u = __float_as_uint(f);
  u32 r = (u + 0x7FFFu + ((u >> 16) & 1u)) >> 16;
  return (u16)r;
}
__device__ __forceinline__ float bf2f(u32 h) { return __uint_as_float(h << 16); }

__device__ __forceinline__ u32 pack2(float a, float b) {
  union { __bf16 h[2]; u32 u; } cv;
  cv.h[0] = (__bf16)a; cv.h[1] = (__bf16)b;
  return cv.u;
}

// ---------------- cast fp32 -> bf16 ----------------------------------------
__global__ __launch_bounds__(256) void castf2b(const float* __restrict__ in,
                                               u16* __restrict__ out) {
  size_t i4 = (size_t)blockIdx.x * 256 + threadIdx.x;
  float4 v = *(const float4*)(in + i4 * 4);
  ushort4 o;
  o.x = f2bf(v.x); o.y = f2bf(v.y); o.z = f2bf(v.z); o.w = f2bf(v.w);
  *(ushort4*)(out + i4 * 4) = o;
}

// ---------------- transpose + cast: W[K][N] fp32 -> WT[N][K] bf16 ----------
__global__ __launch_bounds__(256) void tcast(const float* __restrict__ W,
                                             u16* __restrict__ WT,
                                             int K, int N) {
  __shared__ float tile[32][33];
  const int n0 = blockIdx.x * 32, k0 = blockIdx.y * 32;
  const int r = threadIdx.x >> 3;
  const int c4 = (threadIdx.x & 7) * 4;
  float4 v = *(const float4*)(W + (size_t)(k0 + r) * N + n0 + c4);
  tile[r][c4 + 0] = v.x; tile[r][c4 + 1] = v.y;
  tile[r][c4 + 2] = v.z; tile[r][c4 + 3] = v.w;
  __syncthreads();
  ushort4 o;
  o.x = f2bf(tile[c4 + 0][r]); o.y = f2bf(tile[c4 + 1][r]);
  o.z = f2bf(tile[c4 + 2][r]); o.w = f2bf(tile[c4 + 3][r]);
  *(ushort4*)(WT + (size_t)(n0 + r) * K + k0 + c4) = o;
}

// ---------------- counted-vmcnt MFMA GEMM, BK=32 tri-buffer (R4 best) ------
// C = A @ BT^T.  BM=128, BN=256, BK=32, 512 thr = 8 waves (2M x 4N).
// Tri-buffered LDS (3 x 24KB = 72KB -> 2 blocks/CU, 4 waves/SIMD).
// Raw s_barrier + counted s_waitcnt vmcnt(N): prefetch DMAs (distance 2)
// stay in flight across barriers.  64B LDS rows, 4-chunk XOR swizzle applied
// on the pre-swizzled GLOBAL source (linear LDS dest) and on ds_read chunk.
template <int OUT_BF16>
__global__ __launch_bounds__(512) void gemm8p(const u16* __restrict__ A,
                                              const u16* __restrict__ BT,
                                              void* __restrict__ Cv,
                                              int N, int K) {
  __shared__ u16 lds[3 * 12288];   // per buffer: A 128x32 (4096) | B 256x32 (8192)
  const int t = threadIdx.x;
  const int l = t & 63, w = t >> 6;
  const int lm = l & 15, quad = l >> 4;
  const int wm = w & 1, wn = w >> 1;
  const int m0 = blockIdx.y * 128, n0 = blockIdx.x * 256;
  const int wu = __builtin_amdgcn_readfirstlane(w);

  // staging source pointers (pre-swizzled global col) + uniform LDS dests
  const u16* srcA; int dstA;
  const u16* srcB[2]; int dstB[2];
  {
    int p0 = wu * 64, p = p0 + l;
    int row = p >> 2, c = (p & 3) ^ (row & 3);
    srcA = A + (size_t)(m0 + row) * K + c * 8;
    dstA = p0 * 8;
  }
  #pragma unroll
  for (int i = 0; i < 2; ++i) {
    int p0 = (wu * 2 + i) * 64, p = p0 + l;
    int row = p >> 2, c = (p & 3) ^ (row & 3);
    srcB[i] = BT + (size_t)(n0 + row) * K + c * 8;
    dstB[i] = 4096 + p0 * 8;
  }

  f32x4 acc[4][4];
  #pragma unroll
  for (int i = 0; i < 4; ++i)
    #pragma unroll
    for (int j = 0; j < 4; ++j) acc[i][j] = (f32x4){0.f, 0.f, 0.f, 0.f};

  auto stage = [&](int bsel) {
    u16* buf = &lds[bsel * 12288];
    dma16(srcA, buf + dstA); srcA += 32;
    #pragma unroll
    for (int i = 0; i < 2; ++i) { dma16(srcB[i], buf + dstB[i]); srcB[i] += 32; }
  };

  stage(0); stage(1); stage(2);           // 9 loads/wave in flight (3 K-tiles)

  const int NT = K >> 5;
  int bsel = 0;
  const int xc = lm & 3;
  for (int tI = 0; tI < NT; ++tI) {
    // tile tI's 3 loads are the oldest outstanding; allow 2 newer tiles in flight
    if (tI + 2 < NT)      asm volatile("s_waitcnt vmcnt(6)" ::: "memory");
    else if (tI + 1 < NT) asm volatile("s_waitcnt vmcnt(3)" ::: "memory");
    else                  asm volatile("s_waitcnt vmcnt(0)" ::: "memory");
    asm volatile("s_barrier" ::: "memory");   // raw: no vmcnt(0) drain

    const u16* Ab = &lds[bsel * 12288];
    const u16* Bb = Ab + 4096;
    const int ch = (quad ^ xc) * 8;
    bf16x8 a[4], b[4];
    #pragma unroll
    for (int i = 0; i < 4; ++i)
      a[i] = *(const bf16x8*)&Ab[(wm * 64 + i * 16 + lm) * 32 + ch];
    #pragma unroll
    for (int j = 0; j < 4; ++j)
      b[j] = *(const bf16x8*)&Bb[(wn * 64 + j * 16 + lm) * 32 + ch];
    __builtin_amdgcn_s_setprio(1);
    #pragma unroll
    for (int i = 0; i < 4; ++i)
      #pragma unroll
      for (int j = 0; j < 4; ++j)
        acc[i][j] = __builtin_amdgcn_mfma_f32_16x16x32_bf16(a[i], b[j], acc[i][j], 0, 0, 0);
    __builtin_amdgcn_s_setprio(0);
    asm volatile("s_barrier" ::: "memory");   // all waves done reading buf bsel
    if (tI + 3 < NT) stage(bsel);             // overwrite just-freed buffer
    bsel = (bsel == 2) ? 0 : bsel + 1;
  }

  #pragma unroll
  for (int i = 0; i < 4; ++i) {
    #pragma unroll
    for (int r = 0; r < 4; ++r) {
      size_t gr = (size_t)(m0 + wm * 64 + i * 16 + quad * 4 + r);
      #pragma unroll
      for (int j = 0; j < 4; ++j) {
        int gc = n0 + wn * 64 + j * 16 + lm;
        if (OUT_BF16) ((u16*)Cv)[gr * N + gc] = f2bf(acc[i][j][r]);
        else          ((float*)Cv)[gr * N + gc] = acc[i][j][r];
      }
    }
  }
}

// ---------------- RoPE on K columns only (Q is roped inside attn) ----------
__global__ __launch_bounds__(256) void rope2k(u16* p) {
  const int row = blockIdx.x;
  const int pos = row & (TT - 1);
  u16* base = p + (size_t)row * NKV + 2048;
  const int kh = threadIdx.x >> 6, f = threadIdx.x & 63;
  const int col = kh * 128;
  u32 u = *(const u32*)(base + col + 2 * f);
  float e0 = bf2f(u & 0xffffu);
  float e1 = bf2f(u >> 16);
  __syncthreads();   // all pair-reads done before any write (layout permutes)
  float inv = exp2f((float)f * -0.20762050593046898f);  // 10000^(-f/64)
  float ang = (float)pos * inv;
  float sn, cs;
  sincosf(ang, &sn, &cs);
  base[col + f]      = f2bf(e0 * cs - e1 * sn);
  base[col + 64 + f] = f2bf(e0 * sn + e1 * cs);
}

// ---------------- V transpose: QKV v-part -> Vt[(b*4+vh)*128+d][T] ---------
__global__ __launch_bounds__(256) void vtrans(const u16* __restrict__ QKV,
                                              u16* __restrict__ Vt) {
  __shared__ u16 tl[64][72];
  const int t0 = blockIdx.x * 64;
  const int y  = blockIdx.y;        // 0..7
  const int b  = blockIdx.z;
  #pragma unroll
  for (int i = 0; i < 2; ++i) {
    int idx = threadIdx.x + i * 256;
    int r = idx >> 3, c = (idx & 7) * 8;
    *(uint4*)&tl[r][c] =
        *(const uint4*)(QKV + (size_t)(b * TT + t0 + r) * NKV + 2560 + y * 64 + c);
  }
  __syncthreads();
  const int vh = y >> 1;
  #pragma unroll
  for (int i = 0; i < 2; ++i) {
    int idx = threadIdx.x + i * 256;
    int dr = idx >> 3, tc = (idx & 7) * 8;
    u16 tmp[8];
    #pragma unroll
    for (int j = 0; j < 8; ++j) tmp[j] = tl[tc + j][dr];
    int dloc = (y & 1) * 64 + dr;
    *(uint4*)(Vt + (size_t)((b * KVHN + vh) * HDIM + dloc) * TT + t0 + tc) =
        *(const uint4*)tmp;
  }
}

// ---------------- MFMA flash attention v4 + fused Q-RoPE -------------------
// Body identical to the proven 93us attn4; prologue loads RAW Q pairs and
// applies RoPE + 1/sqrt(HD) scale in-register (pair (f, f+64) maps to
// fragments ks and ks+2 of the SAME lane -> lane-local rotation).
__global__ __launch_bounds__(256, 4) void attn4(const u16* __restrict__ QKV,
                                                const u16* __restrict__ Vt,
                                                u16* __restrict__ Ob) {
  __shared__ u16 KsA[32 * 128], KsB[32 * 128];
  __shared__ u16 VsA[64 * 64], VsB[64 * 64];
  __shared__ u16 Pw[4 * 512];
  const int t = threadIdx.x;
  const int l = t & 63, w = t >> 6;
  const int lm = l & 15, quad = l >> 4;
  const int h = blockIdx.y, b = blockIdx.z;
  const int qbase = (blockIdx.x + (blockIdx.y & 7)) & 31;
  const int qt = (blockIdx.y & 8) ? (31 - qbase) : qbase;
  const int kvh = h >> 2;
  const int q0 = qt * 64;
  const int last = 2 * qt + 1;
  const int wu = __builtin_amdgcn_readfirstlane(w);
  u16* pwv = &Pw[w * 512];
  constexpr float L2E = 1.4426950408889634f;

  f32x4 o[8];
  #pragma unroll
  for (int i = 0; i < 8; ++i) o[i] = (f32x4){0.f, 0.f, 0.f, 0.f};
  float m_ = -1e30f, l_ = 0.f;

  const u16 *kg[2], *vg[2];
  int koff[2], voff[2];
  #pragma unroll
  for (int i = 0; i < 2; ++i) {
    int p0 = (wu * 2 + i) * 64, p = p0 + l;
    int krow = p >> 4, kcp = p & 15, kcl = kcp ^ (krow & 15);
    kg[i] = QKV + (size_t)(b * TT + krow) * NKV + 2048 + kvh * HDIM + kcl * 8;
    koff[i] = p0 * 8;
    int vrow = p >> 3, vphys = p & 7, vcl = vphys ^ (vrow & 7);
    int vd = vrow + (vcl >> 2) * 64, vtch = vcl & 3;
    vg[i] = Vt + (size_t)((b * KVHN + kvh) * HDIM + vd) * TT + vtch * 8;
    voff[i] = p0 * 8;
  }

  #pragma unroll
  for (int i = 0; i < 2; ++i) {
    dma16(kg[i], KsA + koff[i]);
    dma16(vg[i], VsA + voff[i]);
    kg[i] += 32 * NKV;
    vg[i] += 32;
  }

  const int qrow = q0 + w * 16 + lm;

  // Q fragments with fused RoPE + scale (hidden under tile-0 staging)
  bf16x8 qf[4];
  {
    const u16* qp = QKV + (size_t)(b * TT + qrow) * NKV + h * HDIM;
    bf16x8 raw[4];   // [kp][half]: raw pairs at kp*64 + quad*16 + half*8
    #pragma unroll
    for (int i = 0; i < 4; ++i)
      raw[i] = *(const bf16x8*)(qp + (i >> 1) * 64 + quad * 16 + (i & 1) * 8);
    #pragma unroll
    for (int kp = 0; kp < 2; ++kp)
      #pragma unroll
      for (int e = 0; e < 8; ++e) {
        int f = kp * 32 + quad * 8 + e;
        float ang = (float)qrow * exp2f((float)f * -0.20762050593046898f);
        float sn, cs;
        sincosf(ang, &sn, &cs);
        float e0 = (float)raw[kp * 2 + (e >> 2)][(2 * e) & 7];
        float e1 = (float)raw[kp * 2 + (e >> 2)][(2 * e + 1) & 7];
        qf[kp][e]     = (__bf16)((e0 * cs - e1 * sn) * 0.08838834764831845f);
        qf[kp + 2][e] = (__bf16)((e0 * sn + e1 * cs) * 0.08838834764831845f);
      }
  }

  auto body = [&](int kt, const u16* kcur, const u16* vcur, u16* knx, u16* vnx) {
    __syncthreads();
    const bool pf = kt < last;
    if (pf) {
      #pragma unroll
      for (int i = 0; i < 2; ++i) dma16(vg[i], vnx + voff[i]);
    }

    f32x4 s[2];
    s[0] = (f32x4){0.f, 0.f, 0.f, 0.f};
    s[1] = (f32x4){0.f, 0.f, 0.f, 0.f};
    __builtin_amdgcn_s_setprio(1);
    #pragma unroll
    for (int ks = 0; ks < 4; ++ks) {
      #pragma unroll
      for (int mt = 0; mt < 2; ++mt) {
        bf16x8 kb = *(const bf16x8*)&kcur[(mt * 16 + lm) * 128 + (((ks * 4 + quad) ^ lm) * 8)];
        s[mt] = __builtin_amdgcn_mfma_f32_16x16x32_bf16(kb, qf[ks], s[mt], 0, 0, 0);
      }
    }
    __builtin_amdgcn_s_setprio(0);
    if (pf) {
      #pragma unroll
      for (int i = 0; i < 2; ++i) {
        dma16(kg[i], knx + koff[i]);
        kg[i] += 32 * NKV;
        vg[i] += 32;
      }
    }

    if (kt >= 2 * qt) {
      #pragma unroll
      for (int mt = 0; mt < 2; ++mt)
        #pragma unroll
        for (int r = 0; r < 4; ++r) {
          int kv = kt * 32 + mt * 16 + quad * 4 + r;
          if (kv > qrow) s[mt][r] = -1e30f;
        }
    }

    float mx = -1e30f;
    #pragma unroll
    for (int mt = 0; mt < 2; ++mt)
      #pragma unroll
      for (int r = 0; r < 4; ++r) mx = fmaxf(mx, s[mt][r]);
    mx = fmaxf(mx, __shfl_xor(mx, 16));
    mx = fmaxf(mx, __shfl_xor(mx, 32));
    bool upd = mx > m_ + 8.f;
    float mn = upd ? mx : m_;
    float al = upd ? exp2f((m_ - mn) * L2E) : 1.f;
    m_ = mn;
    float sum = 0.f;
    #pragma unroll
    for (int mt = 0; mt < 2; ++mt)
      #pragma unroll
      for (int r = 0; r < 4; ++r) {
        float pv = exp2f((s[mt][r] - mn) * L2E);
        s[mt][r] = pv;
        sum += pv;
      }
    sum += __shfl_xor(sum, 16);
    sum += __shfl_xor(sum, 32);
    l_ = l_ * al + sum;

    #pragma unroll
    for (int mt = 0; mt < 2; ++mt) {
      u32 p01 = pack2(s[mt][0], s[mt][1]);
      u32 p23 = pack2(s[mt][2], s[mt][3]);
      int c = mt * 2 + (quad >> 1);
      int addr = (lm >> 1) * 64 + ((lm & 1) * 4 + (c ^ ((lm >> 1) & 3))) * 8 + (quad & 1) * 4;
      uint2 uv; uv.x = p01; uv.y = p23;
      *(uint2*)&pwv[addr] = uv;
    }
    if (__any(upd)) {
      #pragma unroll
      for (int i = 0; i < 8; ++i)
        #pragma unroll
        for (int r = 0; r < 4; ++r) o[i][r] *= al;
    }

    int paddr = (lm >> 1) * 64 + ((lm & 1) * 4 + (quad ^ ((lm >> 1) & 3))) * 8;
    bf16x8 pb = *(const bf16x8*)&pwv[paddr];
    __builtin_amdgcn_s_setprio(1);
    #pragma unroll
    for (int mt2 = 0; mt2 < 8; ++mt2) {
      int vrow = (mt2 & 3) * 16 + lm;
      int vphys = ((mt2 >> 2) * 4 + quad) ^ (vrow & 7);
      bf16x8 vb = *(const bf16x8*)&vcur[vrow * 64 + vphys * 8];
      o[mt2] = __builtin_amdgcn_mfma_f32_16x16x32_bf16(vb, pb, o[mt2], 0, 0, 0);
    }
    __builtin_amdgcn_s_setprio(0);
  };

  for (int kt = 0; kt <= last; ++kt) {
    if ((kt & 1) == 0) body(kt, KsA, VsA, KsB, VsB);
    else               body(kt, KsB, VsB, KsA, VsA);
  }

  __syncthreads();
  u16* esc = ((w & 2) ? KsB : KsA) + (w & 1) * 2048;
  float inv = 1.f / l_;
  #pragma unroll
  for (int mt2 = 0; mt2 < 8; ++mt2) {
    u32 a0 = pack2(o[mt2][0] * inv, o[mt2][1] * inv);
    u32 a1 = pack2(o[mt2][2] * inv, o[mt2][3] * inv);
    int phys = (mt2 * 2 + (quad >> 1)) ^ (lm & 7);
    int addr = lm * 128 + phys * 8 + (quad & 1) * 4;
    uint2 uv; uv.x = a0; uv.y = a1;
    *(uint2*)&esc[addr] = uv;
  }
  #pragma unroll
  for (int i = 0; i < 4; ++i) {
    int p = i * 64 + l;
    int row = p >> 4, cl = p & 15;
    int cph = cl ^ (row & 7);
    uint4 val = *(const uint4*)&esc[row * 128 + cph * 8];
    *(uint4*)(Ob + (size_t)(b * TT + q0 + w * 16 + row) * DD + h * HDIM + cl * 8) = val;
  }
}

extern "C" void kernel_launch(void* const* d_in, const int* in_sizes, int n_in,
                              void* d_out, int out_size, void* d_ws, size_t ws_size,
                              hipStream_t stream) {
  const float* x  = (const float*)d_in[0];
  const float* Wq = (const float*)d_in[1];
  const float* Wk = (const float*)d_in[2];
  const float* Wv = (const float*)d_in[3];
  const float* Wo = (const float*)d_in[4];
  float* out = (float*)d_out;

  // ws (u16 elems): xb @0 (8M, -> Ob) | WqkvT @8M (6M, -> Vt) | WoT @14.68M (4M)
  u16* xb    = (u16*)d_ws;
  u16* WqkvT = xb + 8388608;
  u16* WoT   = xb + 14680064;
  u16* Vt    = WqkvT;               // alias, live after QKV GEMM
  u16* Ob    = xb;                  // alias, live after QKV GEMM
  u16* QKVb  = (u16*)d_out;         // bf16 [4096][3072] in the 32MB out buffer

  dim3 blk(256);
  castf2b<<<8192, blk, 0, stream>>>(x, xb);
  tcast<<<dim3(64, 64), blk, 0, stream>>>(Wq, WqkvT, DD, DD);
  tcast<<<dim3(16, 64), blk, 0, stream>>>(Wk, WqkvT + (size_t)2048 * DD, DD, 512);
  tcast<<<dim3(16, 64), blk, 0, stream>>>(Wv, WqkvT + (size_t)2560 * DD, DD, 512);
  tcast<<<dim3(64, 64), blk, 0, stream>>>(Wo, WoT, DD, DD);

  gemm8p<1><<<dim3(NKV / 256, 32), dim3(512), 0, stream>>>(xb, WqkvT, QKVb, NKV, DD);
  rope2k<<<BB * TT, blk, 0, stream>>>(QKVb);
  vtrans<<<dim3(32, 8, BB), blk, 0, stream>>>(QKVb, Vt);
  attn4<<<dim3(32, HH, BB), blk, 0, stream>>>(QKVb, Vt, Ob);
  gemm8p<0><<<dim3(DD / 256, 32), dim3(512), 0, stream>>>(Ob, WoT, out, DD, DD);
}

// Round 9
// 318.036 us; speedup vs baseline: 1.0731x; 1.0221x over previous
//
#include <hip/hip_runtime.h>
#include <math.h>

#define BB 2
#define TT 2048
#define DD 2048
#define HH 16
#define KVHN 4
#define HDIM 128
#define NKV 3072   // packed q|k|v row width

typedef unsigned short u16;
typedef unsigned int u32;
typedef __bf16 bf16x8 __attribute__((ext_vector_type(8)));
typedef float  f32x4  __attribute__((ext_vector_type(4)));

#define AS1 __attribute__((address_space(1)))
#define AS3 __attribute__((address_space(3)))

__device__ __forceinline__ void dma16(const u16* g, u16* l) {
  __builtin_amdgcn_global_load_lds((const AS1 u32*)g, (AS3 u32*)l, 16, 0, 0);
}

__device__ __forceinline__ u16 f2bf(float f) {
  u32 u = __float_as_uint(f);
  u32 r = (u + 0x7FFFu + ((u >> 16) & 1u)) >> 16;
  return (u16)r;
}
__device__ __forceinline__ float bf2f(u32 h) { return __uint_as_float(h << 16); }

__device__ __forceinline__ u32 pack2(float a, float b) {
  union { __bf16 h[2]; u32 u; } cv;
  cv.h[0] = (__bf16)a; cv.h[1] = (__bf16)b;
  return cv.u;
}

// HW trig: reduce to revolutions, v_sin/v_cos (D = sin(S0 * 2pi)).
// Added error ~1e-4 abs vs sincosf -- far below bf16 quantization (4e-3).
__device__ __forceinline__ void fast_sincos(float ang, float* sn, float* cs) {
  float rev = ang * 0.15915494309189535f;   // ang / 2pi
  rev -= floorf(rev);                        // [0, 1)
  float s, c;
  asm volatile("v_sin_f32 %0, %1" : "=v"(s) : "v"(rev));
  asm volatile("v_cos_f32 %0, %1" : "=v"(c) : "v"(rev));
  *sn = s; *cs = c;
}

// ---------------- cast fp32 -> bf16 ----------------------------------------
__global__ __launch_bounds__(256) void castf2b(const float* __restrict__ in,
                                               u16* __restrict__ out) {
  size_t i4 = (size_t)blockIdx.x * 256 + threadIdx.x;
  float4 v = *(const float4*)(in + i4 * 4);
  ushort4 o;
  o.x = f2bf(v.x); o.y = f2bf(v.y); o.z = f2bf(v.z); o.w = f2bf(v.w);
  *(ushort4*)(out + i4 * 4) = o;
}

// ---------------- transpose + cast: W[K][N] fp32 -> WT[N][K] bf16 ----------
__global__ __launch_bounds__(256) void tcast(const float* __restrict__ W,
                                             u16* __restrict__ WT,
                                             int K, int N) {
  __shared__ float tile[32][33];
  const int n0 = blockIdx.x * 32, k0 = blockIdx.y * 32;
  const int r = threadIdx.x >> 3;
  const int c4 = (threadIdx.x & 7) * 4;
  float4 v = *(const float4*)(W + (size_t)(k0 + r) * N + n0 + c4);
  tile[r][c4 + 0] = v.x; tile[r][c4 + 1] = v.y;
  tile[r][c4 + 2] = v.z; tile[r][c4 + 3] = v.w;
  __syncthreads();
  ushort4 o;
  o.x = f2bf(tile[c4 + 0][r]); o.y = f2bf(tile[c4 + 1][r]);
  o.z = f2bf(tile[c4 + 2][r]); o.w = f2bf(tile[c4 + 3][r]);
  *(ushort4*)(WT + (size_t)(n0 + r) * K + k0 + c4) = o;
}

// ---------------- counted-vmcnt MFMA GEMM, BK=32 tri-buffer (proven) -------
// C = A @ BT^T.  BM=128, BN=256, BK=32, 512 thr = 8 waves (2M x 4N).
// Tri-buffered LDS (3 x 24KB = 72KB -> 2 blocks/CU, 4 waves/SIMD).
// Raw s_barrier + counted s_waitcnt vmcnt(N): prefetch DMAs (distance 2)
// stay in flight across barriers.  64B LDS rows, 4-chunk XOR swizzle applied
// on the pre-swizzled GLOBAL source (linear LDS dest) and on ds_read chunk.
template <int OUT_BF16>
__global__ __launch_bounds__(512) void gemm8p(const u16* __restrict__ A,
                                              const u16* __restrict__ BT,
                                              void* __restrict__ Cv,
                                              int N, int K) {
  __shared__ u16 lds[3 * 12288];   // per buffer: A 128x32 (4096) | B 256x32 (8192)
  const int t = threadIdx.x;
  const int l = t & 63, w = t >> 6;
  const int lm = l & 15, quad = l >> 4;
  const int wm = w & 1, wn = w >> 1;
  const int m0 = blockIdx.y * 128, n0 = blockIdx.x * 256;
  const int wu = __builtin_amdgcn_readfirstlane(w);

  // staging source pointers (pre-swizzled global col) + uniform LDS dests
  const u16* srcA; int dstA;
  const u16* srcB[2]; int dstB[2];
  {
    int p0 = wu * 64, p = p0 + l;
    int row = p >> 2, c = (p & 3) ^ (row & 3);
    srcA = A + (size_t)(m0 + row) * K + c * 8;
    dstA = p0 * 8;
  }
  #pragma unroll
  for (int i = 0; i < 2; ++i) {
    int p0 = (wu * 2 + i) * 64, p = p0 + l;
    int row = p >> 2, c = (p & 3) ^ (row & 3);
    srcB[i] = BT + (size_t)(n0 + row) * K + c * 8;
    dstB[i] = 4096 + p0 * 8;
  }

  f32x4 acc[4][4];
  #pragma unroll
  for (int i = 0; i < 4; ++i)
    #pragma unroll
    for (int j = 0; j < 4; ++j) acc[i][j] = (f32x4){0.f, 0.f, 0.f, 0.f};

  auto stage = [&](int bsel) {
    u16* buf = &lds[bsel * 12288];
    dma16(srcA, buf + dstA); srcA += 32;
    #pragma unroll
    for (int i = 0; i < 2; ++i) { dma16(srcB[i], buf + dstB[i]); srcB[i] += 32; }
  };

  stage(0); stage(1); stage(2);           // 9 loads/wave in flight (3 K-tiles)

  const int NT = K >> 5;
  int bsel = 0;
  const int xc = lm & 3;
  for (int tI = 0; tI < NT; ++tI) {
    // tile tI's 3 loads are the oldest outstanding; allow 2 newer tiles in flight
    if (tI + 2 < NT)      asm volatile("s_waitcnt vmcnt(6)" ::: "memory");
    else if (tI + 1 < NT) asm volatile("s_waitcnt vmcnt(3)" ::: "memory");
    else                  asm volatile("s_waitcnt vmcnt(0)" ::: "memory");
    asm volatile("s_barrier" ::: "memory");   // raw: no vmcnt(0) drain

    const u16* Ab = &lds[bsel * 12288];
    const u16* Bb = Ab + 4096;
    const int ch = (quad ^ xc) * 8;
    bf16x8 a[4], b[4];
    #pragma unroll
    for (int i = 0; i < 4; ++i)
      a[i] = *(const bf16x8*)&Ab[(wm * 64 + i * 16 + lm) * 32 + ch];
    #pragma unroll
    for (int j = 0; j < 4; ++j)
      b[j] = *(const bf16x8*)&Bb[(wn * 64 + j * 16 + lm) * 32 + ch];
    __builtin_amdgcn_s_setprio(1);
    #pragma unroll
    for (int i = 0; i < 4; ++i)
      #pragma unroll
      for (int j = 0; j < 4; ++j)
        acc[i][j] = __builtin_amdgcn_mfma_f32_16x16x32_bf16(a[i], b[j], acc[i][j], 0, 0, 0);
    __builtin_amdgcn_s_setprio(0);
    asm volatile("s_barrier" ::: "memory");   // all waves done reading buf bsel
    if (tI + 3 < NT) stage(bsel);             // overwrite just-freed buffer
    bsel = (bsel == 2) ? 0 : bsel + 1;
  }

  #pragma unroll
  for (int i = 0; i < 4; ++i) {
    #pragma unroll
    for (int r = 0; r < 4; ++r) {
      size_t gr = (size_t)(m0 + wm * 64 + i * 16 + quad * 4 + r);
      #pragma unroll
      for (int j = 0; j < 4; ++j) {
        int gc = n0 + wn * 64 + j * 16 + lm;
        if (OUT_BF16) ((u16*)Cv)[gr * N + gc] = f2bf(acc[i][j][r]);
        else          ((float*)Cv)[gr * N + gc] = acc[i][j][r];
      }
    }
  }
}

// ---------------- RoPE on K columns only (Q is roped inside attn) ----------
__global__ __launch_bounds__(256) void rope2k(u16* p) {
  const int row = blockIdx.x;
  const int pos = row & (TT - 1);
  u16* base = p + (size_t)row * NKV + 2048;
  const int kh = threadIdx.x >> 6, f = threadIdx.x & 63;
  const int col = kh * 128;
  u32 u = *(const u32*)(base + col + 2 * f);
  float e0 = bf2f(u & 0xffffu);
  float e1 = bf2f(u >> 16);
  __syncthreads();   // all pair-reads done before any write (layout permutes)
  float inv = exp2f((float)f * -0.20762050593046898f);  // 10000^(-f/64)
  float ang = (float)pos * inv;
  float sn, cs;
  fast_sincos(ang, &sn, &cs);
  base[col + f]      = f2bf(e0 * cs - e1 * sn);
  base[col + 64 + f] = f2bf(e0 * sn + e1 * cs);
}

// ---------------- V transpose: QKV v-part -> Vt[(b*4+vh)*128+d][T] ---------
__global__ __launch_bounds__(256) void vtrans(const u16* __restrict__ QKV,
                                              u16* __restrict__ Vt) {
  __shared__ u16 tl[64][72];
  const int t0 = blockIdx.x * 64;
  const int y  = blockIdx.y;        // 0..7
  const int b  = blockIdx.z;
  #pragma unroll
  for (int i = 0; i < 2; ++i) {
    int idx = threadIdx.x + i * 256;
    int r = idx >> 3, c = (idx & 7) * 8;
    *(uint4*)&tl[r][c] =
        *(const uint4*)(QKV + (size_t)(b * TT + t0 + r) * NKV + 2560 + y * 64 + c);
  }
  __syncthreads();
  const int vh = y >> 1;
  #pragma unroll
  for (int i = 0; i < 2; ++i) {
    int idx = threadIdx.x + i * 256;
    int dr = idx >> 3, tc = (idx & 7) * 8;
    u16 tmp[8];
    #pragma unroll
    for (int j = 0; j < 8; ++j) tmp[j] = tl[tc + j][dr];
    int dloc = (y & 1) * 64 + dr;
    *(uint4*)(Vt + (size_t)((b * KVHN + vh) * HDIM + dloc) * TT + t0 + tc) =
        *(const uint4*)tmp;
  }
}

// ---------------- MFMA flash attention v4 + fused Q-RoPE (HW trig) ---------
// Body identical to the proven 93us attn4; prologue loads RAW Q pairs and
// applies RoPE + 1/sqrt(HD) scale in-register; angles via v_sin/v_cos with
// explicit revolution reduction (replaces the 16 libm sincosf that cost
// R6 +6us VALU).
__global__ __launch_bounds__(256, 4) void attn4(const u16* __restrict__ QKV,
                                                const u16* __restrict__ Vt,
                                                u16* __restrict__ Ob) {
  __shared__ u16 KsA[32 * 128], KsB[32 * 128];
  __shared__ u16 VsA[64 * 64], VsB[64 * 64];
  __shared__ u16 Pw[4 * 512];
  const int t = threadIdx.x;
  const int l = t & 63, w = t >> 6;
  const int lm = l & 15, quad = l >> 4;
  const int h = blockIdx.y, b = blockIdx.z;
  const int qbase = (blockIdx.x + (blockIdx.y & 7)) & 31;
  const int qt = (blockIdx.y & 8) ? (31 - qbase) : qbase;
  const int kvh = h >> 2;
  const int q0 = qt * 64;
  const int last = 2 * qt + 1;
  const int wu = __builtin_amdgcn_readfirstlane(w);
  u16* pwv = &Pw[w * 512];
  constexpr float L2E = 1.4426950408889634f;

  f32x4 o[8];
  #pragma unroll
  for (int i = 0; i < 8; ++i) o[i] = (f32x4){0.f, 0.f, 0.f, 0.f};
  float m_ = -1e30f, l_ = 0.f;

  const u16 *kg[2], *vg[2];
  int koff[2], voff[2];
  #pragma unroll
  for (int i = 0; i < 2; ++i) {
    int p0 = (wu * 2 + i) * 64, p = p0 + l;
    int krow = p >> 4, kcp = p & 15, kcl = kcp ^ (krow & 15);
    kg[i] = QKV + (size_t)(b * TT + krow) * NKV + 2048 + kvh * HDIM + kcl * 8;
    koff[i] = p0 * 8;
    int vrow = p >> 3, vphys = p & 7, vcl = vphys ^ (vrow & 7);
    int vd = vrow + (vcl >> 2) * 64, vtch = vcl & 3;
    vg[i] = Vt + (size_t)((b * KVHN + kvh) * HDIM + vd) * TT + vtch * 8;
    voff[i] = p0 * 8;
  }

  #pragma unroll
  for (int i = 0; i < 2; ++i) {
    dma16(kg[i], KsA + koff[i]);
    dma16(vg[i], VsA + voff[i]);
    kg[i] += 32 * NKV;
    vg[i] += 32;
  }

  const int qrow = q0 + w * 16 + lm;

  // Q fragments with fused RoPE + scale (hidden under tile-0 staging)
  bf16x8 qf[4];
  {
    const u16* qp = QKV + (size_t)(b * TT + qrow) * NKV + h * HDIM;
    bf16x8 raw[4];   // [kp][half]: raw pairs at kp*64 + quad*16 + half*8
    #pragma unroll
    for (int i = 0; i < 4; ++i)
      raw[i] = *(const bf16x8*)(qp + (i >> 1) * 64 + quad * 16 + (i & 1) * 8);
    #pragma unroll
    for (int kp = 0; kp < 2; ++kp)
      #pragma unroll
      for (int e = 0; e < 8; ++e) {
        int f = kp * 32 + quad * 8 + e;
        float ang = (float)qrow * exp2f((float)f * -0.20762050593046898f);
        float sn, cs;
        fast_sincos(ang, &sn, &cs);
        float e0 = (float)raw[kp * 2 + (e >> 2)][(2 * e) & 7];
        float e1 = (float)raw[kp * 2 + (e >> 2)][(2 * e + 1) & 7];
        qf[kp][e]     = (__bf16)((e0 * cs - e1 * sn) * 0.08838834764831845f);
        qf[kp + 2][e] = (__bf16)((e0 * sn + e1 * cs) * 0.08838834764831845f);
      }
  }

  auto body = [&](int kt, const u16* kcur, const u16* vcur, u16* knx, u16* vnx) {
    __syncthreads();
    const bool pf = kt < last;
    if (pf) {
      #pragma unroll
      for (int i = 0; i < 2; ++i) dma16(vg[i], vnx + voff[i]);
    }

    f32x4 s[2];
    s[0] = (f32x4){0.f, 0.f, 0.f, 0.f};
    s[1] = (f32x4){0.f, 0.f, 0.f, 0.f};
    __builtin_amdgcn_s_setprio(1);
    #pragma unroll
    for (int ks = 0; ks < 4; ++ks) {
      #pragma unroll
      for (int mt = 0; mt < 2; ++mt) {
        bf16x8 kb = *(const bf16x8*)&kcur[(mt * 16 + lm) * 128 + (((ks * 4 + quad) ^ lm) * 8)];
        s[mt] = __builtin_amdgcn_mfma_f32_16x16x32_bf16(kb, qf[ks], s[mt], 0, 0, 0);
      }
    }
    __builtin_amdgcn_s_setprio(0);
    if (pf) {
      #pragma unroll
      for (int i = 0; i < 2; ++i) {
        dma16(kg[i], knx + koff[i]);
        kg[i] += 32 * NKV;
        vg[i] += 32;
      }
    }

    if (kt >= 2 * qt) {
      #pragma unroll
      for (int mt = 0; mt < 2; ++mt)
        #pragma unroll
        for (int r = 0; r < 4; ++r) {
          int kv = kt * 32 + mt * 16 + quad * 4 + r;
          if (kv > qrow) s[mt][r] = -1e30f;
        }
    }

    float mx = -1e30f;
    #pragma unroll
    for (int mt = 0; mt < 2; ++mt)
      #pragma unroll
      for (int r = 0; r < 4; ++r) mx = fmaxf(mx, s[mt][r]);
    mx = fmaxf(mx, __shfl_xor(mx, 16));
    mx = fmaxf(mx, __shfl_xor(mx, 32));
    bool upd = mx > m_ + 8.f;
    float mn = upd ? mx : m_;
    float al = upd ? exp2f((m_ - mn) * L2E) : 1.f;
    m_ = mn;
    float sum = 0.f;
    #pragma unroll
    for (int mt = 0; mt < 2; ++mt)
      #pragma unroll
      for (int r = 0; r < 4; ++r) {
        float pv = exp2f((s[mt][r] - mn) * L2E);
        s[mt][r] = pv;
        sum += pv;
      }
    sum += __shfl_xor(sum, 16);
    sum += __shfl_xor(sum, 32);
    l_ = l_ * al + sum;

    #pragma unroll
    for (int mt = 0; mt < 2; ++mt) {
      u32 p01 = pack2(s[mt][0], s[mt][1]);
      u32 p23 = pack2(s[mt][2], s[mt][3]);
      int c = mt * 2 + (quad >> 1);
      int addr = (lm >> 1) * 64 + ((lm & 1) * 4 + (c ^ ((lm >> 1) & 3))) * 8 + (quad & 1) * 4;
      uint2 uv; uv.x = p01; uv.y = p23;
      *(uint2*)&pwv[addr] = uv;
    }
    if (__any(upd)) {
      #pragma unroll
      for (int i = 0; i < 8; ++i)
        #pragma unroll
        for (int r = 0; r < 4; ++r) o[i][r] *= al;
    }

    int paddr = (lm >> 1) * 64 + ((lm & 1) * 4 + (quad ^ ((lm >> 1) & 3))) * 8;
    bf16x8 pb = *(const bf16x8*)&pwv[paddr];
    __builtin_amdgcn_s_setprio(1);
    #pragma unroll
    for (int mt2 = 0; mt2 < 8; ++mt2) {
      int vrow = (mt2 & 3) * 16 + lm;
      int vphys = ((mt2 >> 2) * 4 + quad) ^ (vrow & 7);
      bf16x8 vb = *(const bf16x8*)&vcur[vrow * 64 + vphys * 8];
      o[mt2] = __builtin_amdgcn_mfma_f32_16x16x32_bf16(vb, pb, o[mt2], 0, 0, 0);
    }
    __builtin_amdgcn_s_setprio(0);
  };

  for (int kt = 0; kt <= last; ++kt) {
    if ((kt & 1) == 0) body(kt, KsA, VsA, KsB, VsB);
    else               body(kt, KsB, VsB, KsA, VsA);
  }

  __syncthreads();
  u16* esc = ((w & 2) ? KsB : KsA) + (w & 1) * 2048;
  float inv = 1.f / l_;
  #pragma unroll
  for (int mt2 = 0; mt2 < 8; ++mt2) {
    u32 a0 = pack2(o[mt2][0] * inv, o[mt2][1] * inv);
    u32 a1 = pack2(o[mt2][2] * inv, o[mt2][3] * inv);
    int phys = (mt2 * 2 + (quad >> 1)) ^ (lm & 7);
    int addr = lm * 128 + phys * 8 + (quad & 1) * 4;
    uint2 uv; uv.x = a0; uv.y = a1;
    *(uint2*)&esc[addr] = uv;
  }
  #pragma unroll
  for (int i = 0; i < 4; ++i) {
    int p = i * 64 + l;
    int row = p >> 4, cl = p & 15;
    int cph = cl ^ (row & 7);
    uint4 val = *(const uint4*)&esc[row * 128 + cph * 8];
    *(uint4*)(Ob + (size_t)(b * TT + q0 + w * 16 + row) * DD + h * HDIM + cl * 8) = val;
  }
}

extern "C" void kernel_launch(void* const* d_in, const int* in_sizes, int n_in,
                              void* d_out, int out_size, void* d_ws, size_t ws_size,
                              hipStream_t stream) {
  const float* x  = (const float*)d_in[0];
  const float* Wq = (const float*)d_in[1];
  const float* Wk = (const float*)d_in[2];
  const float* Wv = (const float*)d_in[3];
  const float* Wo = (const float*)d_in[4];
  float* out = (float*)d_out;

  // ws (u16 elems): xb @0 (8M, -> Ob) | WqkvT @8M (6M, -> Vt) | WoT @14.68M (4M)
  u16* xb    = (u16*)d_ws;
  u16* WqkvT = xb + 8388608;
  u16* WoT   = xb + 14680064;
  u16* Vt    = WqkvT;               // alias, live after QKV GEMM
  u16* Ob    = xb;                  // alias, live after QKV GEMM
  u16* QKVb  = (u16*)d_out;         // bf16 [4096][3072] in the 32MB out buffer

  dim3 blk(256);
  castf2b<<<8192, blk, 0, stream>>>(x, xb);
  tcast<<<dim3(64, 64), blk, 0, stream>>>(Wq, WqkvT, DD, DD);
  tcast<<<dim3(16, 64), blk, 0, stream>>>(Wk, WqkvT + (size_t)2048 * DD, DD, 512);
  tcast<<<dim3(16, 64), blk, 0, stream>>>(Wv, WqkvT + (size_t)2560 * DD, DD, 512);
  tcast<<<dim3(64, 64), blk, 0, stream>>>(Wo, WoT, DD, DD);

  gemm8p<1><<<dim3(NKV / 256, 32), dim3(512), 0, stream>>>(xb, WqkvT, QKVb, NKV, DD);
  rope2k<<<BB * TT, blk, 0, stream>>>(QKVb);
  vtrans<<<dim3(32, 8, BB), blk, 0, stream>>>(QKVb, Vt);
  attn4<<<dim3(32, HH, BB), blk, 0, stream>>>(QKVb, Vt, Ob);
  gemm8p<0><<<dim3(DD / 256, 32), dim3(512), 0, stream>>>(Ob, WoT, out, DD, DD);
}